// Round 2
// baseline (343.002 us; speedup 1.0000x reference)
//
#include <hip/hip_runtime.h>
#include <math.h>

// PPCALayer fused kernel, MI355X (gfx950) — wave-autonomous version.
// x: [B=64, C=256, HW=3136] fp32, weight: [3136, 15] fp32, out same as x.
//
// Per pixel (b,s): 15 multi-scale channel-group means (scales 1,2,4,8 over
// contiguous channel groups) -> normalize across the 15 features (ddof=0)
// -> dot with weight[s,:] -> sigmoid -> scale x[b,:,s].
//
// Design: each WAVE independently owns 16 spatial positions x 256 channels.
//   lane = (c0<<2)|s4 : c0 = lane>>2 owns channels [16*c0, 16*c0+16),
//                       s4 = lane&3 owns spatials [4*s4, 4*s4+4) as one float4.
// The 256x16 fp32 tile (16 KB) lives entirely in registers (16 float4/lane).
// All reductions are __shfl_xor butterflies over distances 4/8/16/32 (these
// preserve lane&3, i.e. the spatial class). ZERO LDS, ZERO __syncthreads:
// no vmcnt(0) barrier drains, waves never block each other -> memory pipe
// stays saturated. Occupancy is VGPR-bound (~4 waves/SIMD vs 2 in the old
// LDS-staged version).
//
// Key algebra:
//  - mean of the 15 features m = tot/256 EXACTLY equals the scale-1 feature,
//    so the normalized scale-1 feature is 0 and weight[:,0] is dead. z is a
//    dot over only the 14 remaining features, computed distributed with
//    replication-corrected coefficients: a lane's 32-group sum t1 is
//    replicated on 2 lanes (x1/2), 64-group t2 on 4 (x1/4), 128-group t3 on
//    8 (x1/8).
//  - var = (1/15) * sum over features of (f-m)^2 (the f0 term is 0).

constexpr int C_   = 256;
constexpr int HW_  = 3136;   // 56*56
constexpr int B_   = 64;
constexpr int SPW_ = 16;            // spatials per wave
constexpr int TPI_ = HW_ / SPW_;    // 196 tiles per image
constexpr int WPB_ = 4;             // waves per block (block = 256)

__device__ __forceinline__ float4 shx4(float4 a, int m) {
  float4 r;
  r.x = __shfl_xor(a.x, m);
  r.y = __shfl_xor(a.y, m);
  r.z = __shfl_xor(a.z, m);
  r.w = __shfl_xor(a.w, m);
  return r;
}
__device__ __forceinline__ float4 add4(float4 a, float4 b) {
  float4 r; r.x = a.x + b.x; r.y = a.y + b.y; r.z = a.z + b.z; r.w = a.w + b.w;
  return r;
}

__global__ __launch_bounds__(256, 4) void ppca_fused(
    const float* __restrict__ x, const float* __restrict__ wgt,
    float* __restrict__ out)
{
  const int lane = threadIdx.x & 63;
  const int wav  = threadIdx.x >> 6;
  const unsigned W   = blockIdx.x * WPB_ + wav;   // 0..12543
  const unsigned b   = W / TPI_;                  // magic-mul div
  const unsigned til = W - b * TPI_;
  const int sp0 = til * SPW_;

  const int s4 = lane & 3;    // float4 column (4 spatials)
  const int c0 = lane >> 2;   // 16-channel group, 0..15

  const size_t off = (size_t)b * C_ * HW_ + (size_t)c0 * 16 * HW_
                   + (size_t)sp0 + (size_t)(s4 << 2);
  const float* xb = x + off;
  float* ob = out + off;

  // ---- Load the wave's tile: 16 float4 per lane, held in registers.
  // Per instruction: 16 channel rows x one 64B segment each (4 lanes x 16B),
  // 64B-aligned (sp0 multiple of 16) -> coalesced.
  float4 v[16];
  #pragma unroll
  for (int i = 0; i < 16; ++i)
    v[i] = *(const float4*)(xb + (size_t)i * HW_);

  // ---- Per-lane partial: sum of its 16 channels, per spatial component.
  float4 ps = v[0];
  #pragma unroll
  for (int i = 1; i < 16; ++i) ps = add4(ps, v[i]);

  // ---- Butterfly up the group-sum hierarchy (all per-spatial, float4):
  // t1 = 32-group sum, t2 = 64-group, t3 = 128-group, t4 = total(256).
  const float4 t1 = add4(ps, shx4(ps, 4));
  const float4 t2 = add4(t1, shx4(t1, 8));
  const float4 t3 = add4(t2, shx4(t2, 16));
  const float4 t4 = add4(t3, shx4(t3, 32));

  // ---- Centered features (per spatial component; m uniform within s4 class).
  // u1 = f32grp - m (replicated x2), u2 = f64grp - m (x4), u3 = f128grp - m (x8).
  float4 m4;
  m4.x = t4.x * (1.f / 256.f); m4.y = t4.y * (1.f / 256.f);
  m4.z = t4.z * (1.f / 256.f); m4.w = t4.w * (1.f / 256.f);

  // Feature order in weight row: [0:tot(dead), 1-2:128s, 3-6:64s, 7-14:32s].
  const float* wr = wgt + (size_t)sp0 * 15;
  const int i128 = 1 + (c0 >> 3);
  const int i64  = 3 + (c0 >> 2);
  const int i32  = 7 + (c0 >> 1);

  float4 zn, sq;
#define DO_SPATIAL(J, T1c, T2c, T3c, Mc, ZNc, SQc)                           \
  {                                                                          \
    const float* wp = wr + ((s4 << 2) + J) * 15;                             \
    const float w128 = wp[i128];                                             \
    const float w64  = wp[i64];                                              \
    const float w32  = wp[i32];                                              \
    const float u1 = T1c * (1.f / 32.f)  - Mc;                               \
    const float u2 = T2c * (1.f / 64.f)  - Mc;                               \
    const float u3 = T3c * (1.f / 128.f) - Mc;                               \
    ZNc = u1 * w32 * 0.5f + u2 * w64 * 0.25f + u3 * w128 * 0.125f;           \
    SQc = u1 * u1 * 0.5f  + u2 * u2 * 0.25f  + u3 * u3 * 0.125f;             \
  }
  DO_SPATIAL(0, t1.x, t2.x, t3.x, m4.x, zn.x, sq.x)
  DO_SPATIAL(1, t1.y, t2.y, t3.y, m4.y, zn.y, sq.y)
  DO_SPATIAL(2, t1.z, t2.z, t3.z, m4.z, zn.z, sq.z)
  DO_SPATIAL(3, t1.w, t2.w, t3.w, m4.w, zn.w, sq.w)
#undef DO_SPATIAL

  // ---- Butterfly-sum the accumulators across the 16 lanes sharing s4.
  #pragma unroll
  for (int d = 4; d <= 32; d <<= 1) {
    zn = add4(zn, shx4(zn, d));
    sq = add4(sq, shx4(sq, d));
  }

  // ---- Gate per spatial: var = sq/15; z = zn/std; gate = sigmoid(z).
  float4 g;
#define GATE(ZNc, SQc, Gc)                                                   \
  {                                                                          \
    const float var = SQc * (1.f / 15.f);                                    \
    const float inv = 1.f / sqrtf(var);                                      \
    const float z   = ZNc * inv;                                             \
    Gc = 1.f / (1.f + __expf(-z));                                           \
  }
  GATE(zn.x, sq.x, g.x)
  GATE(zn.y, sq.y, g.y)
  GATE(zn.z, sq.z, g.z)
  GATE(zn.w, sq.w, g.w)
#undef GATE

  // ---- Multiply registers by gate, store (same coalesced pattern as load).
  #pragma unroll
  for (int i = 0; i < 16; ++i) {
    float4 vv = v[i];
    vv.x *= g.x; vv.y *= g.y; vv.z *= g.z; vv.w *= g.w;
    *(float4*)(ob + (size_t)i * HW_) = vv;
  }
}

extern "C" void kernel_launch(void* const* d_in, const int* in_sizes, int n_in,
                              void* d_out, int out_size, void* d_ws, size_t ws_size,
                              hipStream_t stream) {
  const float* x = (const float*)d_in[0];      // [64,256,3136] fp32
  const float* w = (const float*)d_in[1];      // [3136,15] fp32
  float* out = (float*)d_out;                  // [64,256,3136] fp32
  (void)in_sizes; (void)n_in; (void)out_size; (void)d_ws; (void)ws_size;

  dim3 grid(B_ * TPI_ / WPB_);   // 12544 waves / 4 = 3136 blocks
  dim3 block(256);
  ppca_fused<<<grid, block, 0, stream>>>(x, w, out);
}